// Round 7
// baseline (2389.139 us; speedup 1.0000x reference)
//
#include <hip/hip_runtime.h>

#define S_LEN 256
#define BATCH 256

typedef _Float16 f16;
typedef _Float16 f16x8 __attribute__((ext_vector_type(8)));
typedef _Float16 f16x4 __attribute__((ext_vector_type(4)));
typedef float f32x4 __attribute__((ext_vector_type(4)));

__device__ inline float sigf(float x) { return 1.f / (1.f + __expf(-x)); }
__device__ inline float tanhf2(float x) { return 2.f * sigf(2.f * x) - 1.f; }

// ---------------- weight f32 -> f16 conversion ----------------
// dst layout (f16 elems): wihf@0, whhf@65536, wihb@131072, whhb@196608,
// swih@262144, swhh@524288, wwih@786432, wwhh@1048576  (total 1310720)
__global__ void k_convert(const float* __restrict__ w3, const float* __restrict__ w4,
                          const float* __restrict__ w6, const float* __restrict__ w7,
                          const float* __restrict__ w9, const float* __restrict__ w10,
                          const float* __restrict__ w12, const float* __restrict__ w13,
                          f16* __restrict__ dst) {
  int i = blockIdx.x * blockDim.x + threadIdx.x;
  const int n = 1310720;
  for (; i < n; i += gridDim.x * blockDim.x) {
    float v;
    if (i < 262144) {
      int m = i >> 16, j = i & 65535;
      v = (m == 0 ? w3 : m == 1 ? w4 : m == 2 ? w6 : w7)[j];
    } else {
      int k = i - 262144;
      int m = k >> 18, j = k & 262143;
      v = (m == 0 ? w9 : m == 1 ? w10 : m == 2 ? w12 : w13)[j];
    }
    dst[i] = (f16)v;
  }
}

__global__ void k_zero(unsigned* __restrict__ p, int n) {
  int i = blockIdx.x * blockDim.x + threadIdx.x;
  for (; i < n; i += gridDim.x * blockDim.x) p[i] = 0u;
}

// ---------------- embedding gather -> Xf [t][b][128] f16 ----------------
__global__ void k_gather(const int* __restrict__ insts, const float* __restrict__ emb,
                         f16* __restrict__ Xf) {
  int gid = blockIdx.x * blockDim.x + threadIdx.x;  // 0..2097151
  int row = gid >> 5;                               // t*B + b
  int ch = gid & 31;
  int t = row >> 8, b = row & 255;
  int v = insts[b * S_LEN + t];
  const float* src = emb + (size_t)v * 128 + ch * 4;
  f16x4 d;
  d[0] = (f16)src[0]; d[1] = (f16)src[1]; d[2] = (f16)src[2]; d[3] = (f16)src[3];
  *(f16x4*)&Xf[(size_t)row * 128 + ch * 4] = d;
}

// ---------------- char BiLSTM: 32 blocks (16 fwd + 16 bwd), Bblk=16 ----------------
// chars output layout: [team][t][row_in_team(16)][256]  (team = batch/16)
__global__ __launch_bounds__(512, 2)
void k_char(const f16* __restrict__ wbuf, const f16* __restrict__ Xf,
            const float* __restrict__ bias_f, const float* __restrict__ bias_b,
            f16* __restrict__ chars) {
  const int bwd = blockIdx.x >> 4;
  const int teamc = blockIdx.x & 15;
  const int m0 = teamc * 16;
  const f16* Wih = wbuf + (bwd ? 131072 : 0);
  const f16* Whh = wbuf + (bwd ? 196608 : 65536);
  const float* bias = bwd ? bias_b : bias_f;

  const int tid = threadIdx.x;
  const int lane = tid & 63;
  const int wave = tid >> 6;
  const int gw = wave >> 1;        // gate 0..3
  const int u0 = (wave & 1) * 64;  // unit offset within gate
  const int l15 = lane & 15;
  const int kb = (lane >> 4) * 8;

  __shared__ f16 xs[2][16][136];
  __shared__ f16 hs[16][136];
  __shared__ float gex[16][520];

  f32x4 fih[4][4], fhh[4][4];
  float bv[4];
#pragma unroll
  for (int tt = 0; tt < 4; ++tt) {
    int col = gw * 128 + u0 + tt * 16 + l15;  // 0..511
    bv[tt] = bias[col];
#pragma unroll
    for (int ks = 0; ks < 4; ++ks) {
      fih[tt][ks] = *(const volatile f32x4*)&Wih[col * 128 + ks * 32 + kb];
      fhh[tt][ks] = *(const volatile f32x4*)&Whh[col * 128 + ks * 32 + kb];
    }
  }

  for (int i = tid; i < 16 * 136; i += 512) ((f16*)hs)[i] = (f16)0.f;
  {
    int mm = tid >> 5, cc = (tid & 31) * 4;
    int t_in = bwd ? (S_LEN - 1) : 0;
    *(f16x4*)&xs[0][mm][cc] =
        *(const f16x4*)&Xf[(size_t)t_in * BATCH * 128 + (m0 + mm) * 128 + cc];
  }
  float cst[4] = {0.f, 0.f, 0.f, 0.f};
  const int cm = tid >> 5;        // cell batch row
  const int cu = (tid & 31) * 4;  // cell unit base
  __syncthreads();

  for (int s = 0; s < S_LEN; ++s) {
    const int par = s & 1;
    f32x4 acc[4];
#pragma unroll
    for (int tt = 0; tt < 4; ++tt) { f32x4 a = {bv[tt], bv[tt], bv[tt], bv[tt]}; acc[tt] = a; }
#pragma unroll
    for (int ks = 0; ks < 4; ++ks) {
      f16x8 ax = *(const f16x8*)&xs[par][l15][ks * 32 + kb];
      f16x8 ah = *(const f16x8*)&hs[l15][ks * 32 + kb];
#pragma unroll
      for (int tt = 0; tt < 4; ++tt) {
        acc[tt] = __builtin_amdgcn_mfma_f32_16x16x32_f16(
            ax, __builtin_bit_cast(f16x8, fih[tt][ks]), acc[tt], 0, 0, 0);
        acc[tt] = __builtin_amdgcn_mfma_f32_16x16x32_f16(
            ah, __builtin_bit_cast(f16x8, fhh[tt][ks]), acc[tt], 0, 0, 0);
      }
    }
    // prefetch next x into regs (independent of recurrence)
    f16x4 xreg;
    const int sn = s + 1;
    if (sn < S_LEN) {
      int t_in = bwd ? (S_LEN - 1 - sn) : sn;
      xreg = *(const f16x4*)&Xf[(size_t)t_in * BATCH * 128 + (m0 + cm) * 128 + cu];
    }
#pragma unroll
    for (int tt = 0; tt < 4; ++tt) {
      int col = gw * 128 + u0 + tt * 16 + l15;
#pragma unroll
      for (int r = 0; r < 4; ++r) gex[(lane >> 4) * 4 + r][col] = acc[tt][r];
    }
    __syncthreads();
    // cell update: thread (cm, cu..cu+3)
    f16x4 hv;
#pragma unroll
    for (int qq = 0; qq < 4; ++qq) {
      int u = cu + qq;
      float gi = gex[cm][u], gf = gex[cm][128 + u], gg = gex[cm][256 + u], go = gex[cm][384 + u];
      float c = sigf(gf) * cst[qq] + sigf(gi) * tanhf2(gg);
      cst[qq] = c;
      hv[qq] = (f16)(sigf(go) * tanhf2(c));
    }
    {
      int t_in = bwd ? (S_LEN - 1 - s) : s;
      int cbase = bwd ? (128 + cu) : cu;
      *(f16x4*)&chars[(size_t)(((teamc * S_LEN + t_in) * 16 + cm) * 256) + cbase] = hv;
      *(f16x4*)&hs[cm][cu] = hv;
      if (sn < S_LEN) *(f16x4*)&xs[par ^ 1][cm][cu] = xreg;
    }
    __syncthreads();
  }
}

// ---------------- sub + word LSTM, stack semantics de-sugared ----------------
// R2 geometry: 16 teams x 16 blocks x 256 thr (4 waves). Critical-path diet:
//  - per-WAVE flags (64/team): each wave drains its own stores (vmcnt(0)) and
//    sets its flag -> no collective-drain barrier, no post-spin barrier.
//  - packed u32 publish (h1<<16)|wh: 1 store / 1 contiguous 64B staging read.
//  - flags[team][64] contiguous -> 64-lane poll = 4 cache lines.
// 2 barriers/step (B1 gates, B4 staging). Spin covers own-block waves' flags,
// so post-spin LDS overwrite is safe (they are past their publish => past B1).
__global__ __launch_bounds__(256, 1)
void k_subword(const f16* __restrict__ wbuf, const f16* __restrict__ chars,
               const int* __restrict__ golds,
               const float* __restrict__ b_sub, const float* __restrict__ b_wrd,
               unsigned* __restrict__ pub, unsigned* __restrict__ flags,
               f16* __restrict__ H2) {
  const int team = blockIdx.x >> 4;
  const int q = blockIdx.x & 15;
  const int m0 = team * 16;
  const int h0 = q * 16;
  const int tid = threadIdx.x, lane = tid & 63, wave = tid >> 6;
  const int l15 = lane & 15, kb = (lane >> 4) * 8;

  const f16* sWih = wbuf + 262144;
  const f16* sWhh = wbuf + 524288;
  const f16* wWih = wbuf + 786432;
  const f16* wWhh = wbuf + 1048576;

  __shared__ f16 xs_s[16][264];
  __shared__ f16 h1_s[16][264];
  __shared__ f16 wh_s[16][264];
  __shared__ float gexS[16][68];
  __shared__ float gexW[16][68];
  __shared__ int golds_s[16][256];

  // weight fragments (volatile: not rematerializable; perf-neutral, proven)
  f32x4 fsi[8], fsh[8], fwi[8], fwh[8];
  const int wr = wave * 256 + h0 + l15;
#pragma unroll
  for (int ks = 0; ks < 8; ++ks) {
    fsi[ks] = *(const volatile f32x4*)&sWih[wr * 256 + ks * 32 + kb];
    fsh[ks] = *(const volatile f32x4*)&sWhh[wr * 256 + ks * 32 + kb];
    fwi[ks] = *(const volatile f32x4*)&wWih[wr * 256 + ks * 32 + kb];
    fwh[ks] = *(const volatile f32x4*)&wWhh[wr * 256 + ks * 32 + kb];
  }
  const float bS = b_sub[wr], bW = b_wrd[wr];

  for (int i = tid; i < 16 * 256; i += 256)
    golds_s[i >> 8][i & 255] = golds[(m0 + (i >> 8)) * S_LEN + (i & 255)];
  for (int i = tid; i < 16 * 264; i += 256) {
    ((f16*)xs_s)[i] = (f16)0.f;
    ((f16*)h1_s)[i] = (f16)0.f;
    ((f16*)wh_s)[i] = (f16)0.f;
  }
  const int cm = tid >> 4, cj = tid & 15;
  const int sr = tid >> 4;            // staging row
  const int sc = (tid & 15) * 16;     // staging col base (16 units per thread)
  float c_sub = 0.f, c_wrd = 0.f, wh_reg = 0.f;
  __syncthreads();

  for (int i = 0; i <= S_LEN; ++i) {
    const bool doW = (i > 0), doS = (i < S_LEN);
    const int slotbase = ((i & 1) * 16 + team) << 12;  // *4096 u32

    // chars[i] prefetch into regs (team-blocked layout -> XCD-L2-resident)
    f16x4 chpre[4];
    if (doS) {
#pragma unroll
      for (int p = 0; p < 4; ++p)
        chpre[p] = *(const f16x4*)&chars[(size_t)(((team * S_LEN + i) * 16 + sr) * 256) +
                                         sc + p * 4];
    }

    f32x4 accW = {bW, bW, bW, bW};
    f32x4 accS = {bS, bS, bS, bS};
    if (doW) {
#pragma unroll
      for (int ks = 0; ks < 8; ++ks) {
        f16x8 a1 = *(const f16x8*)&h1_s[l15][ks * 32 + kb];
        f16x8 aw = *(const f16x8*)&wh_s[l15][ks * 32 + kb];
        accW = __builtin_amdgcn_mfma_f32_16x16x32_f16(
            a1, __builtin_bit_cast(f16x8, fwi[ks]), accW, 0, 0, 0);
        accW = __builtin_amdgcn_mfma_f32_16x16x32_f16(
            aw, __builtin_bit_cast(f16x8, fwh[ks]), accW, 0, 0, 0);
      }
    }
    if (doS) {
      const bool keep = (i > 0) && (golds_s[l15][i > 0 ? i - 1 : 0] == 0);
      f16x8 z8 = {};
#pragma unroll
      for (int ks = 0; ks < 8; ++ks) {
        f16x8 axv = *(const f16x8*)&xs_s[l15][ks * 32 + kb];
        f16x8 a1 = *(const f16x8*)&h1_s[l15][ks * 32 + kb];
        a1 = keep ? a1 : z8;  // per-row state reset (stack jump reads zeros)
        accS = __builtin_amdgcn_mfma_f32_16x16x32_f16(
            axv, __builtin_bit_cast(f16x8, fsi[ks]), accS, 0, 0, 0);
        accS = __builtin_amdgcn_mfma_f32_16x16x32_f16(
            a1, __builtin_bit_cast(f16x8, fsh[ks]), accS, 0, 0, 0);
      }
    }
#pragma unroll
    for (int r = 0; r < 4; ++r) {
      if (doW) gexW[(lane >> 4) * 4 + r][wave * 16 + l15] = accW[r];
      if (doS) gexS[(lane >> 4) * 4 + r][wave * 16 + l15] = accS[r];
    }
    __syncthreads();  // B1: gates visible

    const int gprev = (i > 0) ? golds_s[cm][i - 1] : 1;
    if (doW) {  // word cell for t = i-1; advance iff golds[b][t] != 0
      float gi = gexW[cm][cj], gf = gexW[cm][16 + cj], gg = gexW[cm][32 + cj],
            go = gexW[cm][48 + cj];
      float c2 = sigf(gf) * c_wrd + sigf(gi) * tanhf2(gg);
      float h2 = sigf(go) * tanhf2(c2);
      bool adv = (gprev != 0);
      if (adv) { c_wrd = c2; wh_reg = h2; }
      H2[(size_t)(i - 1) * BATCH * 256 + (m0 + cm) * 256 + h0 + cj] = (f16)h2;
    }
    if (doS) {  // sub cell for t = i; reset iff i==0 or golds[b][i-1] != 0
      float gi = gexS[cm][cj], gf = gexS[cm][16 + cj], gg = gexS[cm][32 + cj],
            go = gexS[cm][48 + cj];
      float cp = (gprev == 0) ? c_sub : 0.f;
      float c1 = sigf(gf) * cp + sigf(gi) * tanhf2(gg);
      c_sub = c1;
      f16 h1 = (f16)(sigf(go) * tanhf2(c1));
      // packed publish: (h1 << 16) | wh_state
      unsigned val = ((unsigned)__builtin_bit_cast(unsigned short, h1) << 16) |
                     (unsigned)__builtin_bit_cast(unsigned short, (f16)wh_reg);
      __hip_atomic_store(&pub[slotbase + cm * 256 + h0 + cj], val, __ATOMIC_RELAXED,
                         __HIP_MEMORY_SCOPE_AGENT);
    }

    if (doS) {
      // per-wave drain + flag; then all-lane coalesced poll of 64 wave-flags
      asm volatile("s_waitcnt vmcnt(0)" ::: "memory");
      if ((tid & 63) == 0)
        __hip_atomic_store(&flags[team * 64 + q * 4 + wave], (unsigned)(i + 1),
                           __ATOMIC_RELAXED, __HIP_MEMORY_SCOPE_AGENT);
      const unsigned tgt = (unsigned)(i + 1);
      while (true) {
        unsigned v = __hip_atomic_load(&flags[team * 64 + lane], __ATOMIC_RELAXED,
                                       __HIP_MEMORY_SCOPE_AGENT);
        if (__all(v >= tgt)) break;
        __builtin_amdgcn_s_sleep(1);
      }
      asm volatile("" ::: "memory");  // staging loads stay below the spin
      // bulk staging read (one contiguous 64B per thread) + LDS unpack
#pragma unroll
      for (int half = 0; half < 2; ++half) {
        union { unsigned short s[8]; f16x8 v; } uh, uw;
#pragma unroll
        for (int k = 0; k < 8; ++k) {
          unsigned v = __hip_atomic_load(&pub[slotbase + sr * 256 + sc + half * 8 + k],
                                         __ATOMIC_RELAXED, __HIP_MEMORY_SCOPE_AGENT);
          uh.s[k] = (unsigned short)(v >> 16);
          uw.s[k] = (unsigned short)(v & 0xffffu);
        }
        *(f16x8*)&h1_s[sr][sc + half * 8] = uh.v;
        *(f16x8*)&wh_s[sr][sc + half * 8] = uw.v;
      }
#pragma unroll
      for (int p = 0; p < 4; ++p) *(f16x4*)&xs_s[sr][sc + p * 4] = chpre[p];
      __syncthreads();  // B4: LDS staged for next iter
    }
  }
}

// ---------------- classifier: out[b][t][c] = [h2 ; chars] @ clsW.T + clsb ----------------
__global__ __launch_bounds__(256)
void k_cls(const f16* __restrict__ H2, const f16* __restrict__ chars,
           const float* __restrict__ clsW, const float* __restrict__ clsb,
           float* __restrict__ out) {
  const int w = (blockIdx.x << 2) | (threadIdx.x >> 6);  // row = t*B + b
  const int lane = threadIdx.x & 63;
  const int t = w >> 8, b = w & 255;
  const f16* h2p = H2 + (size_t)w * 256;
  const f16* chp = chars + (size_t)(((b >> 4) * S_LEN + t) * 16 + (b & 15)) * 256;
  float s0 = 0.f, s1 = 0.f;
  f16x4 hv = *(const f16x4*)&h2p[lane * 4];
  f16x4 cv = *(const f16x4*)&chp[lane * 4];
#pragma unroll
  for (int qq = 0; qq < 4; ++qq) {
    int u = lane * 4 + qq;
    s0 += (float)hv[qq] * clsW[u] + (float)cv[qq] * clsW[256 + u];
    s1 += (float)hv[qq] * clsW[512 + u] + (float)cv[qq] * clsW[768 + u];
  }
#pragma unroll
  for (int off = 32; off >= 1; off >>= 1) {
    s0 += __shfl_down(s0, off);
    s1 += __shfl_down(s1, off);
  }
  if (lane == 0) {
    out[((size_t)b * S_LEN + t) * 2 + 0] = s0 + clsb[0];
    out[((size_t)b * S_LEN + t) * 2 + 1] = s1 + clsb[1];
  }
}

extern "C" void kernel_launch(void* const* d_in, const int* in_sizes, int n_in,
                              void* d_out, int out_size, void* d_ws, size_t ws_size,
                              hipStream_t stream) {
  const int* insts = (const int*)d_in[0];
  const int* golds = (const int*)d_in[1];
  const float* emb = (const float*)d_in[2];
  const float* wihf = (const float*)d_in[3];
  const float* whhf = (const float*)d_in[4];
  const float* bf = (const float*)d_in[5];
  const float* wihb = (const float*)d_in[6];
  const float* whhb = (const float*)d_in[7];
  const float* bb = (const float*)d_in[8];
  const float* swih = (const float*)d_in[9];
  const float* swhh = (const float*)d_in[10];
  const float* sb = (const float*)d_in[11];
  const float* wwih = (const float*)d_in[12];
  const float* wwhh = (const float*)d_in[13];
  const float* wb = (const float*)d_in[14];
  const float* clsW = (const float*)d_in[15];
  const float* clsb = (const float*)d_in[16];
  float* out = (float*)d_out;

  // workspace layout (bytes)
  const size_t OFF_W = 0;                       // 2,621,440
  const size_t OFF_XF = 2621440;                // +16,777,216 (dead after k_char)
  const size_t OFF_PUB = OFF_XF + 4194304;      // +524,288 u32 pub (overlaid on Xf tail)
  const size_t OFF_FLAGS = OFF_PUB + 524288;    // +4,096
  const size_t OFF_CHARS = 19398656;            // +33,554,432 (team-blocked layout)
  const size_t OFF_H2 = 52953088;               // +33,554,432
  const size_t TOTAL = 87048192;
  if (ws_size < TOTAL) return;

  char* ws = (char*)d_ws;
  f16* wbuf = (f16*)(ws + OFF_W);
  f16* Xf = (f16*)(ws + OFF_XF);
  f16* chars = (f16*)(ws + OFF_CHARS);
  f16* H2 = (f16*)(ws + OFF_H2);
  unsigned* pub = (unsigned*)(ws + OFF_PUB);
  unsigned* flags = (unsigned*)(ws + OFF_FLAGS);

  hipLaunchKernelGGL(k_convert, dim3(1024), dim3(256), 0, stream, wihf, whhf, wihb, whhb,
                     swih, swhh, wwih, wwhh, wbuf);
  hipLaunchKernelGGL(k_gather, dim3(8192), dim3(256), 0, stream, insts, emb, Xf);
  hipLaunchKernelGGL(k_char, dim3(32), dim3(512), 0, stream, wbuf, Xf, bf, bb, chars);
  // zero the per-wave flags (overlaid on Xf -> must run after k_char)
  hipLaunchKernelGGL(k_zero, dim3(4), dim3(256), 0, stream, (unsigned*)(ws + OFF_FLAGS),
                     1024);
  hipLaunchKernelGGL(k_subword, dim3(256), dim3(256), 0, stream, wbuf, chars, golds, sb, wb,
                     pub, flags, H2);
  hipLaunchKernelGGL(k_cls, dim3(16384), dim3(256), 0, stream, H2, chars, clsW, clsb, out);
}

// Round 8
// 1382.423 us; speedup vs baseline: 1.7282x; 1.7282x over previous
//
#include <hip/hip_runtime.h>

#define S_LEN 256
#define BATCH 256

typedef _Float16 f16;
typedef _Float16 f16x8 __attribute__((ext_vector_type(8)));
typedef _Float16 f16x4 __attribute__((ext_vector_type(4)));
typedef float f32x4 __attribute__((ext_vector_type(4)));
typedef unsigned u32x4 __attribute__((ext_vector_type(4)));

__device__ inline float sigf(float x) { return 1.f / (1.f + __expf(-x)); }
__device__ inline float tanhf2(float x) { return 2.f * sigf(2.f * x) - 1.f; }

// ---------------- weight f32 -> f16 conversion ----------------
// dst layout (f16 elems): wihf@0, whhf@65536, wihb@131072, whhb@196608,
// swih@262144, swhh@524288, wwih@786432, wwhh@1048576  (total 1310720)
__global__ void k_convert(const float* __restrict__ w3, const float* __restrict__ w4,
                          const float* __restrict__ w6, const float* __restrict__ w7,
                          const float* __restrict__ w9, const float* __restrict__ w10,
                          const float* __restrict__ w12, const float* __restrict__ w13,
                          f16* __restrict__ dst) {
  int i = blockIdx.x * blockDim.x + threadIdx.x;
  const int n = 1310720;
  for (; i < n; i += gridDim.x * blockDim.x) {
    float v;
    if (i < 262144) {
      int m = i >> 16, j = i & 65535;
      v = (m == 0 ? w3 : m == 1 ? w4 : m == 2 ? w6 : w7)[j];
    } else {
      int k = i - 262144;
      int m = k >> 18, j = k & 262143;
      v = (m == 0 ? w9 : m == 1 ? w10 : m == 2 ? w12 : w13)[j];
    }
    dst[i] = (f16)v;
  }
}

__global__ void k_zero(unsigned* __restrict__ p, int n) {
  int i = blockIdx.x * blockDim.x + threadIdx.x;
  for (; i < n; i += gridDim.x * blockDim.x) p[i] = 0u;
}

// ---------------- embedding gather -> Xf [t][b][128] f16 ----------------
__global__ void k_gather(const int* __restrict__ insts, const float* __restrict__ emb,
                         f16* __restrict__ Xf) {
  int gid = blockIdx.x * blockDim.x + threadIdx.x;  // 0..2097151
  int row = gid >> 5;                               // t*B + b
  int ch = gid & 31;
  int t = row >> 8, b = row & 255;
  int v = insts[b * S_LEN + t];
  const float* src = emb + (size_t)v * 128 + ch * 4;
  f16x4 d;
  d[0] = (f16)src[0]; d[1] = (f16)src[1]; d[2] = (f16)src[2]; d[3] = (f16)src[3];
  *(f16x4*)&Xf[(size_t)row * 128 + ch * 4] = d;
}

// ---------------- char BiLSTM: 32 blocks (16 fwd + 16 bwd), Bblk=16 ----------------
// chars output layout: [team][t][row_in_team(16)][256]  (team = batch/16)
__global__ __launch_bounds__(512, 2)
void k_char(const f16* __restrict__ wbuf, const f16* __restrict__ Xf,
            const float* __restrict__ bias_f, const float* __restrict__ bias_b,
            f16* __restrict__ chars) {
  const int bwd = blockIdx.x >> 4;
  const int teamc = blockIdx.x & 15;
  const int m0 = teamc * 16;
  const f16* Wih = wbuf + (bwd ? 131072 : 0);
  const f16* Whh = wbuf + (bwd ? 196608 : 65536);
  const float* bias = bwd ? bias_b : bias_f;

  const int tid = threadIdx.x;
  const int lane = tid & 63;
  const int wave = tid >> 6;
  const int gw = wave >> 1;        // gate 0..3
  const int u0 = (wave & 1) * 64;  // unit offset within gate
  const int l15 = lane & 15;
  const int kb = (lane >> 4) * 8;

  __shared__ f16 xs[2][16][136];
  __shared__ f16 hs[16][136];
  __shared__ float gex[16][520];

  f32x4 fih[4][4], fhh[4][4];
  float bv[4];
#pragma unroll
  for (int tt = 0; tt < 4; ++tt) {
    int col = gw * 128 + u0 + tt * 16 + l15;  // 0..511
    bv[tt] = bias[col];
#pragma unroll
    for (int ks = 0; ks < 4; ++ks) {
      fih[tt][ks] = *(const volatile f32x4*)&Wih[col * 128 + ks * 32 + kb];
      fhh[tt][ks] = *(const volatile f32x4*)&Whh[col * 128 + ks * 32 + kb];
    }
  }

  for (int i = tid; i < 16 * 136; i += 512) ((f16*)hs)[i] = (f16)0.f;
  {
    int mm = tid >> 5, cc = (tid & 31) * 4;
    int t_in = bwd ? (S_LEN - 1) : 0;
    *(f16x4*)&xs[0][mm][cc] =
        *(const f16x4*)&Xf[(size_t)t_in * BATCH * 128 + (m0 + mm) * 128 + cc];
  }
  float cst[4] = {0.f, 0.f, 0.f, 0.f};
  const int cm = tid >> 5;        // cell batch row
  const int cu = (tid & 31) * 4;  // cell unit base
  __syncthreads();

  for (int s = 0; s < S_LEN; ++s) {
    const int par = s & 1;
    f32x4 acc[4];
#pragma unroll
    for (int tt = 0; tt < 4; ++tt) { f32x4 a = {bv[tt], bv[tt], bv[tt], bv[tt]}; acc[tt] = a; }
#pragma unroll
    for (int ks = 0; ks < 4; ++ks) {
      f16x8 ax = *(const f16x8*)&xs[par][l15][ks * 32 + kb];
      f16x8 ah = *(const f16x8*)&hs[l15][ks * 32 + kb];
#pragma unroll
      for (int tt = 0; tt < 4; ++tt) {
        acc[tt] = __builtin_amdgcn_mfma_f32_16x16x32_f16(
            ax, __builtin_bit_cast(f16x8, fih[tt][ks]), acc[tt], 0, 0, 0);
        acc[tt] = __builtin_amdgcn_mfma_f32_16x16x32_f16(
            ah, __builtin_bit_cast(f16x8, fhh[tt][ks]), acc[tt], 0, 0, 0);
      }
    }
    // prefetch next x into regs (independent of recurrence)
    f16x4 xreg;
    const int sn = s + 1;
    if (sn < S_LEN) {
      int t_in = bwd ? (S_LEN - 1 - sn) : sn;
      xreg = *(const f16x4*)&Xf[(size_t)t_in * BATCH * 128 + (m0 + cm) * 128 + cu];
    }
#pragma unroll
    for (int tt = 0; tt < 4; ++tt) {
      int col = gw * 128 + u0 + tt * 16 + l15;
#pragma unroll
      for (int r = 0; r < 4; ++r) gex[(lane >> 4) * 4 + r][col] = acc[tt][r];
    }
    __syncthreads();
    // cell update: thread (cm, cu..cu+3)
    f16x4 hv;
#pragma unroll
    for (int qq = 0; qq < 4; ++qq) {
      int u = cu + qq;
      float gi = gex[cm][u], gf = gex[cm][128 + u], gg = gex[cm][256 + u], go = gex[cm][384 + u];
      float c = sigf(gf) * cst[qq] + sigf(gi) * tanhf2(gg);
      cst[qq] = c;
      hv[qq] = (f16)(sigf(go) * tanhf2(c));
    }
    {
      int t_in = bwd ? (S_LEN - 1 - s) : s;
      int cbase = bwd ? (128 + cu) : cu;
      *(f16x4*)&chars[(size_t)(((teamc * S_LEN + t_in) * 16 + cm) * 256) + cbase] = hv;
      *(f16x4*)&hs[cm][cu] = hv;
      if (sn < S_LEN) *(f16x4*)&xs[par ^ 1][cm][cu] = xreg;
    }
    __syncthreads();
  }
}

// ---------------- sub + word LSTM, stack semantics de-sugared ----------------
// R2 skeleton verbatim (16 teams x 16 blocks x 256 thr, block flags, wave0
// 16-lane poll, B2/B3/B4). Deltas vs R2:
//  - packed u32 publish (h1<<16)|wh : 1 sc1 store/thread (was 2)
//  - staging: 4x inline-asm global_load_dwordx4 sc0 sc1 (64B in 4 wide
//    coherent loads; R7's 16 scalar atomic loads were the regression)
__global__ __launch_bounds__(256, 1)
void k_subword(const f16* __restrict__ wbuf, const f16* __restrict__ chars,
               const int* __restrict__ golds,
               const float* __restrict__ b_sub, const float* __restrict__ b_wrd,
               unsigned* __restrict__ pub, unsigned* __restrict__ flags,
               f16* __restrict__ H2) {
  const int team = blockIdx.x >> 4;
  const int q = blockIdx.x & 15;
  const int m0 = team * 16;
  const int h0 = q * 16;
  const int tid = threadIdx.x, lane = tid & 63, wave = tid >> 6;
  const int l15 = lane & 15, kb = (lane >> 4) * 8;

  const f16* sWih = wbuf + 262144;
  const f16* sWhh = wbuf + 524288;
  const f16* wWih = wbuf + 786432;
  const f16* wWhh = wbuf + 1048576;

  __shared__ f16 xs_s[16][264];
  __shared__ f16 h1_s[16][264];
  __shared__ f16 wh_s[16][264];
  __shared__ float gexS[16][68];
  __shared__ float gexW[16][68];
  __shared__ int golds_s[16][256];

  // weight fragments (volatile: not rematerializable; perf-neutral, proven)
  f32x4 fsi[8], fsh[8], fwi[8], fwh[8];
  const int wr = wave * 256 + h0 + l15;
#pragma unroll
  for (int ks = 0; ks < 8; ++ks) {
    fsi[ks] = *(const volatile f32x4*)&sWih[wr * 256 + ks * 32 + kb];
    fsh[ks] = *(const volatile f32x4*)&sWhh[wr * 256 + ks * 32 + kb];
    fwi[ks] = *(const volatile f32x4*)&wWih[wr * 256 + ks * 32 + kb];
    fwh[ks] = *(const volatile f32x4*)&wWhh[wr * 256 + ks * 32 + kb];
  }
  const float bS = b_sub[wr], bW = b_wrd[wr];

  for (int i = tid; i < 16 * 256; i += 256)
    golds_s[i >> 8][i & 255] = golds[(m0 + (i >> 8)) * S_LEN + (i & 255)];
  for (int i = tid; i < 16 * 264; i += 256) {
    ((f16*)xs_s)[i] = (f16)0.f;
    ((f16*)h1_s)[i] = (f16)0.f;
    ((f16*)wh_s)[i] = (f16)0.f;
  }
  const int cm = tid >> 4, cj = tid & 15;
  const int sr = tid >> 4;            // staging row
  const int sc = (tid & 15) * 16;     // staging col base (16 units per thread)
  float c_sub = 0.f, c_wrd = 0.f, wh_reg = 0.f;
  __syncthreads();

  for (int i = 0; i <= S_LEN; ++i) {
    const bool doW = (i > 0), doS = (i < S_LEN);
    const int slotbase = ((i & 1) * 16 + team) << 12;  // u32 index, 4096/team-slot

    // chars[i] prefetch into regs (team-blocked layout -> L2-resident)
    f16x4 chpre[4];
    if (doS) {
#pragma unroll
      for (int p = 0; p < 4; ++p)
        chpre[p] = *(const f16x4*)&chars[(size_t)(((team * S_LEN + i) * 16 + sr) * 256) +
                                         sc + p * 4];
    }

    f32x4 accW = {bW, bW, bW, bW};
    f32x4 accS = {bS, bS, bS, bS};
    if (doW) {
#pragma unroll
      for (int ks = 0; ks < 8; ++ks) {
        f16x8 a1 = *(const f16x8*)&h1_s[l15][ks * 32 + kb];
        f16x8 aw = *(const f16x8*)&wh_s[l15][ks * 32 + kb];
        accW = __builtin_amdgcn_mfma_f32_16x16x32_f16(
            a1, __builtin_bit_cast(f16x8, fwi[ks]), accW, 0, 0, 0);
        accW = __builtin_amdgcn_mfma_f32_16x16x32_f16(
            aw, __builtin_bit_cast(f16x8, fwh[ks]), accW, 0, 0, 0);
      }
    }
    if (doS) {
      const bool keep = (i > 0) && (golds_s[l15][i > 0 ? i - 1 : 0] == 0);
      f16x8 z8 = {};
#pragma unroll
      for (int ks = 0; ks < 8; ++ks) {
        f16x8 axv = *(const f16x8*)&xs_s[l15][ks * 32 + kb];
        f16x8 a1 = *(const f16x8*)&h1_s[l15][ks * 32 + kb];
        a1 = keep ? a1 : z8;  // per-row state reset (stack jump reads zeros)
        accS = __builtin_amdgcn_mfma_f32_16x16x32_f16(
            axv, __builtin_bit_cast(f16x8, fsi[ks]), accS, 0, 0, 0);
        accS = __builtin_amdgcn_mfma_f32_16x16x32_f16(
            a1, __builtin_bit_cast(f16x8, fsh[ks]), accS, 0, 0, 0);
      }
    }
#pragma unroll
    for (int r = 0; r < 4; ++r) {
      if (doW) gexW[(lane >> 4) * 4 + r][wave * 16 + l15] = accW[r];
      if (doS) gexS[(lane >> 4) * 4 + r][wave * 16 + l15] = accS[r];
    }
    __syncthreads();  // B1: gates visible

    const int gprev = (i > 0) ? golds_s[cm][i - 1] : 1;
    if (doW) {  // word cell for t = i-1; advance iff golds[b][t] != 0
      float gi = gexW[cm][cj], gf = gexW[cm][16 + cj], gg = gexW[cm][32 + cj],
            go = gexW[cm][48 + cj];
      float c2 = sigf(gf) * c_wrd + sigf(gi) * tanhf2(gg);
      float h2 = sigf(go) * tanhf2(c2);
      bool adv = (gprev != 0);
      if (adv) { c_wrd = c2; wh_reg = h2; }
      H2[(size_t)(i - 1) * BATCH * 256 + (m0 + cm) * 256 + h0 + cj] = (f16)h2;
    }
    if (doS) {  // sub cell for t = i; reset iff i==0 or golds[b][i-1] != 0
      float gi = gexS[cm][cj], gf = gexS[cm][16 + cj], gg = gexS[cm][32 + cj],
            go = gexS[cm][48 + cj];
      float cp = (gprev == 0) ? c_sub : 0.f;
      float c1 = sigf(gf) * cp + sigf(gi) * tanhf2(gg);
      c_sub = c1;
      f16 h1 = (f16)(sigf(go) * tanhf2(c1));
      // packed publish: (h1 << 16) | wh_state  — single sc1 store
      unsigned val = ((unsigned)__builtin_bit_cast(unsigned short, h1) << 16) |
                     (unsigned)__builtin_bit_cast(unsigned short, (f16)wh_reg);
      __hip_atomic_store(&pub[slotbase + cm * 256 + h0 + cj], val, __ATOMIC_RELAXED,
                         __HIP_MEMORY_SCOPE_AGENT);
    }
    __syncthreads();  // B2: waitcnt vmcnt(0) — all sc1 publish stores acked at LLC

    if (doS) {
      if (tid == 0)
        __hip_atomic_store(&flags[(team * 16 + q) * 16], (unsigned)(i + 1), __ATOMIC_RELAXED,
                           __HIP_MEMORY_SCOPE_AGENT);
      if (tid < 64) {
        const unsigned tgt = (unsigned)(i + 1);
        while (true) {
          unsigned v = tgt;
          if (lane < 16)
            v = __hip_atomic_load(&flags[(team * 16 + lane) * 16], __ATOMIC_RELAXED,
                                  __HIP_MEMORY_SCOPE_AGENT);
          if (__all(v >= tgt)) break;
          __builtin_amdgcn_s_sleep(1);
        }
      }
      asm volatile("" ::: "memory");  // staging stays below the spin
      __syncthreads();  // B3: team barrier passed
      // staging: 64B per thread via 4 wide coherent loads (sc0 sc1 = bypass
      // L1/L2 -> LLC-fresh), single vmcnt drain inside the asm block
      u32x4 w0, w1, w2, w3;
      {
        const unsigned* pb = &pub[slotbase + sr * 256 + sc];
        asm volatile(
            "global_load_dwordx4 %0, %4, off sc0 sc1\n\t"
            "global_load_dwordx4 %1, %5, off sc0 sc1\n\t"
            "global_load_dwordx4 %2, %6, off sc0 sc1\n\t"
            "global_load_dwordx4 %3, %7, off sc0 sc1\n\t"
            "s_waitcnt vmcnt(0)"
            : "=&v"(w0), "=&v"(w1), "=&v"(w2), "=&v"(w3)
            : "v"(pb), "v"(pb + 4), "v"(pb + 8), "v"(pb + 12));
      }
      union { unsigned short s[8]; f16x8 v; } uh0, uw0, uh1, uw1;
#pragma unroll
      for (int k = 0; k < 4; ++k) {
        uh0.s[k] = (unsigned short)(w0[k] >> 16);
        uw0.s[k] = (unsigned short)(w0[k] & 0xffffu);
        uh0.s[4 + k] = (unsigned short)(w1[k] >> 16);
        uw0.s[4 + k] = (unsigned short)(w1[k] & 0xffffu);
        uh1.s[k] = (unsigned short)(w2[k] >> 16);
        uw1.s[k] = (unsigned short)(w2[k] & 0xffffu);
        uh1.s[4 + k] = (unsigned short)(w3[k] >> 16);
        uw1.s[4 + k] = (unsigned short)(w3[k] & 0xffffu);
      }
      *(f16x8*)&h1_s[sr][sc] = uh0.v;
      *(f16x8*)&wh_s[sr][sc] = uw0.v;
      *(f16x8*)&h1_s[sr][sc + 8] = uh1.v;
      *(f16x8*)&wh_s[sr][sc + 8] = uw1.v;
#pragma unroll
      for (int p = 0; p < 4; ++p) *(f16x4*)&xs_s[sr][sc + p * 4] = chpre[p];
      __syncthreads();  // B4: LDS staged for next iter
    }
  }
}

// ---------------- classifier: out[b][t][c] = [h2 ; chars] @ clsW.T + clsb ----------------
__global__ __launch_bounds__(256)
void k_cls(const f16* __restrict__ H2, const f16* __restrict__ chars,
           const float* __restrict__ clsW, const float* __restrict__ clsb,
           float* __restrict__ out) {
  const int w = (blockIdx.x << 2) | (threadIdx.x >> 6);  // row = t*B + b
  const int lane = threadIdx.x & 63;
  const int t = w >> 8, b = w & 255;
  const f16* h2p = H2 + (size_t)w * 256;
  const f16* chp = chars + (size_t)(((b >> 4) * S_LEN + t) * 16 + (b & 15)) * 256;
  float s0 = 0.f, s1 = 0.f;
  f16x4 hv = *(const f16x4*)&h2p[lane * 4];
  f16x4 cv = *(const f16x4*)&chp[lane * 4];
#pragma unroll
  for (int qq = 0; qq < 4; ++qq) {
    int u = lane * 4 + qq;
    s0 += (float)hv[qq] * clsW[u] + (float)cv[qq] * clsW[256 + u];
    s1 += (float)hv[qq] * clsW[512 + u] + (float)cv[qq] * clsW[768 + u];
  }
#pragma unroll
  for (int off = 32; off >= 1; off >>= 1) {
    s0 += __shfl_down(s0, off);
    s1 += __shfl_down(s1, off);
  }
  if (lane == 0) {
    out[((size_t)b * S_LEN + t) * 2 + 0] = s0 + clsb[0];
    out[((size_t)b * S_LEN + t) * 2 + 1] = s1 + clsb[1];
  }
}

extern "C" void kernel_launch(void* const* d_in, const int* in_sizes, int n_in,
                              void* d_out, int out_size, void* d_ws, size_t ws_size,
                              hipStream_t stream) {
  const int* insts = (const int*)d_in[0];
  const int* golds = (const int*)d_in[1];
  const float* emb = (const float*)d_in[2];
  const float* wihf = (const float*)d_in[3];
  const float* whhf = (const float*)d_in[4];
  const float* bf = (const float*)d_in[5];
  const float* wihb = (const float*)d_in[6];
  const float* whhb = (const float*)d_in[7];
  const float* bb = (const float*)d_in[8];
  const float* swih = (const float*)d_in[9];
  const float* swhh = (const float*)d_in[10];
  const float* sb = (const float*)d_in[11];
  const float* wwih = (const float*)d_in[12];
  const float* wwhh = (const float*)d_in[13];
  const float* wb = (const float*)d_in[14];
  const float* clsW = (const float*)d_in[15];
  const float* clsb = (const float*)d_in[16];
  float* out = (float*)d_out;

  // workspace layout (bytes)
  const size_t OFF_W = 0;                       // 2,621,440
  const size_t OFF_XF = 2621440;                // +16,777,216 (dead after k_char)
  const size_t OFF_PUB = OFF_XF + 4194304;      // +524,288 (u32 pub, overlaid on Xf)
  const size_t OFF_FLAGS = OFF_PUB + 524288;    // +16,384
  const size_t OFF_CHARS = 19398656;            // +33,554,432 (team-blocked layout)
  const size_t OFF_H2 = 52953088;               // +33,554,432
  const size_t TOTAL = 87048192;
  if (ws_size < TOTAL) return;

  char* ws = (char*)d_ws;
  f16* wbuf = (f16*)(ws + OFF_W);
  f16* Xf = (f16*)(ws + OFF_XF);
  f16* chars = (f16*)(ws + OFF_CHARS);
  f16* H2 = (f16*)(ws + OFF_H2);
  unsigned* pub = (unsigned*)(ws + OFF_PUB);
  unsigned* flags = (unsigned*)(ws + OFF_FLAGS);

  hipLaunchKernelGGL(k_convert, dim3(1024), dim3(256), 0, stream, wihf, whhf, wihb, whhb,
                     swih, swhh, wwih, wwhh, wbuf);
  hipLaunchKernelGGL(k_gather, dim3(8192), dim3(256), 0, stream, insts, emb, Xf);
  hipLaunchKernelGGL(k_char, dim3(32), dim3(512), 0, stream, wbuf, Xf, bf, bb, chars);
  // zero the block flags (overlaid on Xf -> must run after k_char)
  hipLaunchKernelGGL(k_zero, dim3(16), dim3(256), 0, stream, (unsigned*)(ws + OFF_FLAGS),
                     4096);
  hipLaunchKernelGGL(k_subword, dim3(256), dim3(256), 0, stream, wbuf, chars, golds, sb, wb,
                     pub, flags, H2);
  hipLaunchKernelGGL(k_cls, dim3(16384), dim3(256), 0, stream, H2, chars, clsW, clsb, out);
}